// Round 1
// baseline (651.600 us; speedup 1.0000x reference)
//
#include <hip/hip_runtime.h>
#include <math.h>

#define N_TOK 32768
#define M_EMB 1024
#define D_DIM 128
#define BN 16

// workspace layout (bytes)
#define WS_ET  0                    // float e_t[128][1024]  (512 KB)
#define WS_E2  (512*1024)           // float e2[1024]
#define WS_CNT (WS_E2 + 4096)      // int counts[1024]
#define WS_SS  (WS_CNT + 4096)     // float sum((x-q)^2) accumulator
#define WS_ENT (WS_SS + 4)         // float sum(p*logp) accumulator

__device__ __forceinline__ ushort f2bf(float f) {
    unsigned x = __float_as_uint(f);
    unsigned r = (x + 0x7fffu + ((x >> 16) & 1u)) >> 16;
    return (ushort)r;
}

__global__ void k_zero(char* ws) {
    int* cnt = (int*)(ws + WS_CNT);
    for (int i = threadIdx.x; i < M_EMB; i += 256) cnt[i] = 0;
    if (threadIdx.x == 0) {
        *(float*)(ws + WS_SS) = 0.f;
        *(float*)(ws + WS_ENT) = 0.f;
    }
}

// transpose embedding into e_t[k][m] and compute e2[m]
__global__ void k_prep(const float* __restrict__ emb, char* ws) {
    float* et = (float*)(ws + WS_ET);
    float* e2 = (float*)(ws + WS_E2);
    int m = blockIdx.x;
    int k = threadIdx.x;  // 128 threads
    float v = emb[m * D_DIM + k];
    et[k * M_EMB + m] = v;
    float s = v * v;
    #pragma unroll
    for (int off = 32; off >= 1; off >>= 1) s += __shfl_down(s, off);
    __shared__ float p[2];
    if ((threadIdx.x & 63) == 0) p[threadIdx.x >> 6] = s;
    __syncthreads();
    if (threadIdx.x == 0) e2[m] = p[0] + p[1];
}

__global__ __launch_bounds__(256) void k_main(
    const float* __restrict__ x, const float* __restrict__ emb,
    const float* __restrict__ lvq, const float* __restrict__ u,
    float* __restrict__ out, char* ws)
{
    __shared__ __align__(16) float x_s[BN * D_DIM];     // 8 KB
    __shared__ __align__(16) float Sc[4 * M_EMB];       // 16 KB (4-row score chunk)
    __shared__ __align__(16) ushort w_s[BN * M_EMB];    // 32 KB (bf16 weights)
    __shared__ float x2_s[BN];

    const float* et = (const float*)(ws + WS_ET);
    const float* e2 = (const float*)(ws + WS_E2);
    int* cnt = (int*)(ws + WS_CNT);
    float* ws_ss = (float*)(ws + WS_SS);
    float* ws_ent = (float*)(ws + WS_ENT);

    const int t = threadIdx.x;
    const int n0 = blockIdx.x * BN;
    const float prec = expf(-lvq[0]);
    const float hp = 0.5f * prec;

    if (t < BN) x2_s[t] = 0.f;
    __syncthreads();

    // ---- stage x tile + x2 ----
    {
        const float4* xg = (const float4*)(x + (size_t)n0 * D_DIM);
        float4* xs4 = (float4*)x_s;
        #pragma unroll
        for (int i = 0; i < 2; i++) {
            int f = t + i * 256;  // 0..511 float4s; row = f/32
            float4 v = xg[f];
            xs4[f] = v;
            float s = v.x*v.x + v.y*v.y + v.z*v.z + v.w*v.w;
            atomicAdd(&x2_s[f >> 5], s);
        }
    }
    __syncthreads();

    // ---- phase 1: logits GEMM, scores in registers ----
    // thread t owns cols 4t..4t+3, all 16 rows
    float acc[BN][4];
    #pragma unroll
    for (int r = 0; r < BN; r++)
        #pragma unroll
        for (int j = 0; j < 4; j++) acc[r][j] = 0.f;

    const float4* et4 = (const float4*)et;
    const float4* xs4 = (const float4*)x_s;
    #pragma unroll 2
    for (int kg = 0; kg < 32; kg++) {
        float ev[4][4];
        #pragma unroll
        for (int kk = 0; kk < 4; kk++) {
            float4 tmp = et4[(kg*4 + kk)*256 + t];
            ev[kk][0] = tmp.x; ev[kk][1] = tmp.y; ev[kk][2] = tmp.z; ev[kk][3] = tmp.w;
        }
        #pragma unroll
        for (int r = 0; r < BN; r++) {
            float4 xv4 = xs4[r*32 + kg];
            float xv[4] = {xv4.x, xv4.y, xv4.z, xv4.w};
            #pragma unroll
            for (int kk = 0; kk < 4; kk++)
                #pragma unroll
                for (int j = 0; j < 4; j++)
                    acc[r][j] = fmaf(xv[kk], ev[kk][j], acc[r][j]);
        }
    }
    // epilogue: xe -> logits = -(hp*((x2 - 2*xe) + e2))
    {
        float4 e2v = ((const float4*)e2)[t];
        float e2a[4] = {e2v.x, e2v.y, e2v.z, e2v.w};
        #pragma unroll
        for (int r = 0; r < BN; r++) {
            float xx = x2_s[r];
            #pragma unroll
            for (int j = 0; j < 4; j++) {
                float dd = hp * ((xx - 2.f * acc[r][j]) + e2a[j]);
                acc[r][j] = -dd;
            }
        }
    }

    // ---- phase 2: per-row stats + gumbel softmax weights (4-row chunks) ----
    const int wvid = t >> 6, lane = t & 63;
    float ent_loc = 0.f;
    for (int c = 0; c < 4; c++) {
        #pragma unroll
        for (int rl = 0; rl < 4; rl++) {
            int r = c*4 + rl;
            ((float4*)Sc)[rl*256 + t] = make_float4(acc[r][0], acc[r][1], acc[r][2], acc[r][3]);
        }
        __syncthreads();
        {
            int r = c*4 + wvid;
            int n = n0 + r;
            float* row = Sc + wvid * M_EMB;
            // max + first-argmax (== first-argmin of distances)
            float bv = -INFINITY; int bi = M_EMB;
            #pragma unroll
            for (int i = 0; i < 16; i++) {
                int m = lane + 64*i;
                float v = row[m];
                if (v > bv) { bv = v; bi = m; }
            }
            #pragma unroll
            for (int off = 32; off >= 1; off >>= 1) {
                float ov = __shfl_xor(bv, off);
                int oi = __shfl_xor(bi, off);
                if (ov > bv || (ov == bv && oi < bi)) { bv = ov; bi = oi; }
            }
            float mx = bv;
            float S = 0.f, T = 0.f;
            #pragma unroll
            for (int i = 0; i < 16; i++) {
                float v = row[lane + 64*i] - mx;
                float e = expf(v);
                S += e; T += e * v;
            }
            #pragma unroll
            for (int off = 32; off >= 1; off >>= 1) {
                S += __shfl_xor(S, off); T += __shfl_xor(T, off);
            }
            // gumbel path (TAU = 1)
            const float EPS = 1.1920929e-07f, OME = 0.99999988f;
            float mg = -INFINITY;
            #pragma unroll
            for (int i = 0; i < 16; i++) {
                int m = lane + 64*i;
                float uv = u[(size_t)n * M_EMB + m];
                uv = fminf(fmaxf(uv, EPS), OME);
                float g = row[m] - logf(-logf(uv));
                row[m] = g;
                mg = fmaxf(mg, g);
            }
            #pragma unroll
            for (int off = 32; off >= 1; off >>= 1) mg = fmaxf(mg, __shfl_xor(mg, off));
            float Sg = 0.f;
            #pragma unroll
            for (int i = 0; i < 16; i++) Sg += expf(row[lane + 64*i] - mg);
            #pragma unroll
            for (int off = 32; off >= 1; off >>= 1) Sg += __shfl_xor(Sg, off);
            float inv = 1.f / Sg;
            ushort* wrow = w_s + r * M_EMB;
            #pragma unroll
            for (int i = 0; i < 16; i++) {
                int m = lane + 64*i;
                wrow[m] = f2bf(expf(row[m] - mg) * inv);
            }
            if (lane == 0) {
                ent_loc += T / S - logf(S);
                out[(size_t)N_TOK * D_DIM + n] = (float)bi;
                atomicAdd(&cnt[bi], 1);
            }
        }
        __syncthreads();
    }
    if (lane == 0) atomicAdd(ws_ent, ent_loc);

    // ---- phase 3: quantized = W @ embedding ----
    const int d = t & 127, rp = t >> 7;
    float q[8];
    #pragma unroll
    for (int j = 0; j < 8; j++) q[j] = 0.f;
    #pragma unroll 2
    for (int mg4 = 0; mg4 < 256; mg4++) {
        float eb[4];
        #pragma unroll
        for (int kk = 0; kk < 4; kk++) eb[kk] = emb[(mg4*4 + kk) * D_DIM + d];
        #pragma unroll
        for (int j = 0; j < 8; j++) {
            int r = rp * 8 + j;
            uint2 wvv = *(const uint2*)&w_s[r * M_EMB + mg4*4];
            float w0 = __uint_as_float(wvv.x << 16);
            float w1 = __uint_as_float(wvv.x & 0xffff0000u);
            float w2 = __uint_as_float(wvv.y << 16);
            float w3 = __uint_as_float(wvv.y & 0xffff0000u);
            q[j] = fmaf(w0, eb[0], q[j]);
            q[j] = fmaf(w1, eb[1], q[j]);
            q[j] = fmaf(w2, eb[2], q[j]);
            q[j] = fmaf(w3, eb[3], q[j]);
        }
    }
    float ssl = 0.f;
    #pragma unroll
    for (int j = 0; j < 8; j++) {
        int r = rp*8 + j, n = n0 + r;
        out[(size_t)n * D_DIM + d] = q[j];
        float df = x_s[r * D_DIM + d] - q[j];
        ssl += df * df;
    }
    #pragma unroll
    for (int off = 32; off >= 1; off >>= 1) ssl += __shfl_down(ssl, off);
    if (lane == 0) atomicAdd(ws_ss, ssl);
}

__global__ void k_final(const float* __restrict__ lvq, float* __restrict__ out, char* ws) {
    const int* cnt = (const int*)(ws + WS_CNT);
    float s = 0.f;
    for (int i = threadIdx.x; i < M_EMB; i += 256) {
        float avg = (float)cnt[i] * (1.f / N_TOK);
        s += avg * logf(avg + 1e-10f);
    }
    #pragma unroll
    for (int off = 32; off >= 1; off >>= 1) s += __shfl_down(s, off);
    __shared__ float p[4];
    if ((threadIdx.x & 63) == 0) p[threadIdx.x >> 6] = s;
    __syncthreads();
    if (threadIdx.x == 0) {
        float tot = p[0] + p[1] + p[2] + p[3];
        float perp = expf(-tot);
        float prec = expf(-lvq[0]);
        float loss = 0.5f * prec * (*(float*)(ws + WS_SS)) + (*(float*)(ws + WS_ENT));
        out[(size_t)N_TOK * D_DIM + N_TOK] = loss;
        out[(size_t)N_TOK * D_DIM + N_TOK + 1] = perp;
    }
}

extern "C" void kernel_launch(void* const* d_in, const int* in_sizes, int n_in,
                              void* d_out, int out_size, void* d_ws, size_t ws_size,
                              hipStream_t stream) {
    const float* x   = (const float*)d_in[0];
    const float* emb = (const float*)d_in[1];
    const float* lvq = (const float*)d_in[2];
    const float* u   = (const float*)d_in[3];
    float* out = (float*)d_out;
    char* ws = (char*)d_ws;
    k_zero<<<dim3(1), dim3(256), 0, stream>>>(ws);
    k_prep<<<dim3(M_EMB), dim3(128), 0, stream>>>(emb, ws);
    k_main<<<dim3(N_TOK / BN), dim3(256), 0, stream>>>(x, emb, lvq, u, out, ws);
    k_final<<<dim3(1), dim3(256), 0, stream>>>(lvq, out, ws);
}